// Round 4
// baseline (666.044 us; speedup 1.0000x reference)
//
#include <hip/hip_runtime.h>
#include <math.h>

#define NBF 4104             // B*F = 8*513
#define XT_FLOATS 16809984   // 8*513*8*512

// Static device scratch; fully overwritten before read each call -> deterministic.
__device__ float d_partials[NBF];
__device__ float d_scales[8];

__global__ __launch_bounds__(256, 4) void iss_main(
    const float* __restrict__ g_r,
    const float* __restrict__ g_xre,
    const float* __restrict__ g_xim,
    const float* __restrict__ g_Qre,
    const float* __restrict__ g_Qim,
    float* __restrict__ g_out,
    const int qmode,        // 2 = interleaved re,im pairs; 1 = real part only
    const int xt_off)       // float offset where the xt region begins
{
    __shared__ float  s_xr[8][512];
    __shared__ float  s_xi[8][512];
    __shared__ float2 s_V [8][8][9];   // padded row stride
    __shared__ float2 s_Q [8][8];
    __shared__ float  s_part[4];

    const int tid = threadIdx.x;
    const int bf  = blockIdx.x;
    const size_t base = (size_t)bf * 4096;

    // ---- stage x_re, x_im into LDS (float4, coalesced); Q into s_Q ----
    {
        const float4* xr4 = (const float4*)(g_xre + base);
        const float4* xi4 = (const float4*)(g_xim + base);
        float4* sxr = (float4*)&s_xr[0][0];
        float4* sxi = (float4*)&s_xi[0][0];
        #pragma unroll
        for (int i = 0; i < 4; ++i) {
            const int idx = tid + (i << 8);
            sxr[idx] = xr4[idx];
            sxi[idx] = xi4[idx];
        }
        if (tid < 64)
            s_Q[tid>>3][tid&7] = make_float2(g_Qre[(size_t)bf*64 + tid],
                                             g_Qim[(size_t)bf*64 + tid]);
    }
    __syncthreads();

    // ---- phase A: V[k][m][n] = (1/T) sum_t max(r,1e-3) x_m conj(x_n) ----
    const int k  = tid >> 5;      // 8 k's, 32 threads each
    const int tc = tid & 31;
    // prefetch r straight from global (single-use; no LDS staging)
    float rbuf[16];
    {
        const float* rrow = g_r + base + (k << 9) + tc;
        #pragma unroll
        for (int it = 0; it < 16; ++it) rbuf[it] = rrow[it << 5];
    }

    float accd[8] = {0,0,0,0,0,0,0,0};
    float accr[28], acci[28];
    #pragma unroll
    for (int p = 0; p < 28; ++p) { accr[p] = 0.f; acci[p] = 0.f; }

    #pragma unroll
    for (int it = 0; it < 16; ++it) {
        const int t = tc + (it << 5);
        const float rw = fmaxf(rbuf[it], 1e-3f);
        float xr[8], xi[8];
        #pragma unroll
        for (int m = 0; m < 8; ++m) { xr[m] = s_xr[m][t]; xi[m] = s_xi[m][t]; }
        int p = 0;
        #pragma unroll
        for (int m = 0; m < 8; ++m) {
            const float yr = rw * xr[m], yi = rw * xi[m];
            accd[m] += yr*xr[m] + yi*xi[m];
            #pragma unroll
            for (int n = m+1; n < 8; ++n, ++p) {
                accr[p] += yr*xr[n] + yi*xi[n];
                acci[p] += yi*xr[n] - yr*xi[n];
            }
        }
    }

    // butterfly reduce across the 32 threads sharing k (offsets<=16 stay in half-wave)
    #pragma unroll
    for (int m = 0; m < 8; ++m) {
        #pragma unroll
        for (int off = 16; off >= 1; off >>= 1) accd[m] += __shfl_xor(accd[m], off, 64);
    }
    #pragma unroll
    for (int p = 0; p < 28; ++p) {
        #pragma unroll
        for (int off = 16; off >= 1; off >>= 1) accr[p] += __shfl_xor(accr[p], off, 64);
        #pragma unroll
        for (int off = 16; off >= 1; off >>= 1) acci[p] += __shfl_xor(acci[p], off, 64);
    }

    if (tc == 0) {
        const float invT = 1.0f / 512.0f;
        float d[8]; float tr = 0.f;
        #pragma unroll
        for (int m = 0; m < 8; ++m) { d[m] = accd[m]*invT; tr += d[m]; }
        const float e = fmaxf(tr, 1.0f) * 1e-6f;
        #pragma unroll
        for (int m = 0; m < 8; ++m) s_V[k][m][m] = make_float2(d[m] + e, 0.f);
        int p = 0;
        #pragma unroll
        for (int m = 0; m < 8; ++m) {
            #pragma unroll
            for (int n = m+1; n < 8; ++n, ++p) {
                const float vr = accr[p]*invT, vi = acci[p]*invT;
                s_V[k][m][n] = make_float2(vr,  vi);
                s_V[k][n][m] = make_float2(vr, -vi);
            }
        }
    }
    __syncthreads();

    // ---- phase B: wave-synchronous, zero barriers, all waves redundant ----
    // lane (kp,mm) owns Q[kp][mm]; V row kept in registers; row-kk of Q via shuffles.
    {
        const int lane = tid & 63;
        const int kp = lane >> 3, mm = lane & 7;
        float vRr[8], vRi[8];
        #pragma unroll
        for (int n = 0; n < 8; ++n) {
            const float2 V = s_V[kp][mm][n];
            vRr[n] = V.x; vRi[n] = V.y;
        }
        const float2 Q0 = s_Q[kp][mm];
        float qre = Q0.x, qim = Q0.y;

        #pragma unroll
        for (int step = 0; step < 16; ++step) {
            const int kk = step & 7;
            // snapshot row kk of Q (pre-update values)
            float qnr[8], qni[8];
            #pragma unroll
            for (int n = 0; n < 8; ++n) {
                qnr[n] = __shfl(qre, (kk<<3)+n, 64);
                qni[n] = __shfl(qim, (kk<<3)+n, 64);
            }
            const float qmr = __shfl(qre, (kk<<3)+mm, 64);  // q_old[own m]
            const float qmi = __shfl(qim, (kk<<3)+mm, 64);

            // Vq = V_row . conj(q)
            float vqr = 0.f, vqi = 0.f;
            #pragma unroll
            for (int n = 0; n < 8; ++n) {
                vqr += vRr[n]*qnr[n] + vRi[n]*qni[n];
                vqi += vRi[n]*qnr[n] - vRr[n]*qni[n];
            }
            // p_m = Re(q_m * Vq_m);  t = Q_own * Vq_own (no conj)
            float p   = qmr*vqr - qmi*vqi;
            float tre = qre*vqr - qim*vqi;
            float tim = qre*vqi + qim*vqr;
            // reduce over m within each 8-lane group (lane bits 0..2)
            #pragma unroll
            for (int off = 1; off < 8; off <<= 1) {
                p   += __shfl_xor(p,   off, 64);
                tre += __shfl_xor(tre, off, 64);
                tim += __shfl_xor(tim, off, 64);
            }
            const float qvq = fmaxf(p, 1e-6f);
            float vr_, vi_;
            if (kp == kk) { vr_ = 1.0f - rsqrtf(qvq); vi_ = 0.f; }
            else { const float inv = 1.0f / qvq; vr_ = tre*inv; vi_ = tim*inv; }
            // Q_own -= v * q_old[m]
            qre -= vr_*qmr - vi_*qmi;
            qim -= vr_*qmi + vi_*qmr;
        }

        if (tid < 64) {
            s_Q[kp][mm] = make_float2(qre, qim);
            if (qmode == 2) {
                g_out[(size_t)bf*128 + tid*2]     = qre;
                g_out[(size_t)bf*128 + tid*2 + 1] = qim;
            } else {
                g_out[(size_t)bf*64 + tid] = qre;
            }
        }
    }
    __syncthreads();

    // ---- phase C: xt = |Q x|^2 (unnormalized), float4 I/O, block partial sum ----
    float lsum = 0.f;
    float* out_xt = g_out + xt_off;
    #pragma unroll
    for (int j = 0; j < 4; ++j) {
        const int idx4 = tid + (j << 8);       // 1024 float4 slots
        const int m  = idx4 >> 7;
        const int t0 = (idx4 & 127) << 2;      // 4 consecutive t
        float qxr[4] = {0,0,0,0}, qxi[4] = {0,0,0,0};
        #pragma unroll
        for (int n = 0; n < 8; ++n) {
            const float2 Qv = s_Q[m][n];
            const float4 xr = *(const float4*)&s_xr[n][t0];
            const float4 xi = *(const float4*)&s_xi[n][t0];
            qxr[0] += Qv.x*xr.x - Qv.y*xi.x;  qxi[0] += Qv.x*xi.x + Qv.y*xr.x;
            qxr[1] += Qv.x*xr.y - Qv.y*xi.y;  qxi[1] += Qv.x*xi.y + Qv.y*xr.y;
            qxr[2] += Qv.x*xr.z - Qv.y*xi.z;  qxi[2] += Qv.x*xi.z + Qv.y*xr.z;
            qxr[3] += Qv.x*xr.w - Qv.y*xi.w;  qxi[3] += Qv.x*xi.w + Qv.y*xr.w;
        }
        float4 pw;
        pw.x = qxr[0]*qxr[0] + qxi[0]*qxi[0];
        pw.y = qxr[1]*qxr[1] + qxi[1]*qxi[1];
        pw.z = qxr[2]*qxr[2] + qxi[2]*qxi[2];
        pw.w = qxr[3]*qxr[3] + qxi[3]*qxi[3];
        *(float4*)&out_xt[base + ((size_t)idx4 << 2)] = pw;
        lsum += pw.x + pw.y + pw.z + pw.w;
    }
    #pragma unroll
    for (int off = 32; off >= 1; off >>= 1) lsum += __shfl_xor(lsum, off, 64);
    if ((tid & 63) == 0) s_part[tid >> 6] = lsum;
    __syncthreads();
    if (tid == 0) d_partials[bf] = s_part[0] + s_part[1] + s_part[2] + s_part[3];
}

__global__ __launch_bounds__(256) void iss_scale()
{
    const int b = blockIdx.x, tid = threadIdx.x;
    __shared__ float sp[4];
    float s = 0.f;
    for (int i = tid; i < 513; i += 256) s += d_partials[b*513 + i];
    #pragma unroll
    for (int off = 32; off >= 1; off >>= 1) s += __shfl_xor(s, off, 64);
    if ((tid & 63) == 0) sp[tid >> 6] = s;
    __syncthreads();
    if (tid == 0) d_scales[b] = (sp[0]+sp[1]+sp[2]+sp[3]) / (513.0f * 8.0f * 512.0f);
}

__global__ __launch_bounds__(256) void iss_norm(
    float* __restrict__ g_out,
    const int nq4,     // Q region in float4s  (= xt_off/4)
    const int qb4,     // float4s per batch in Q region
    const int nt4)     // total float4s (= out_size/4)
{
    float4* o4 = (float4*)g_out;
    for (int i = blockIdx.x*256 + threadIdx.x; i < nt4; i += gridDim.x*256) {
        float s;
        if (i < nq4) {
            const int b = i / qb4;
            s = rsqrtf(fmaxf(d_scales[b], 1e-6f));
        } else {
            const int j = i - nq4;
            const int b = j / 525312;          // xt float4s per batch
            s = 1.0f / d_scales[b];
        }
        float4 v = o4[i];
        v.x *= s; v.y *= s; v.z *= s; v.w *= s;
        o4[i] = v;
    }
}

extern "C" void kernel_launch(void* const* d_in, const int* in_sizes, int n_in,
                              void* d_out, int out_size, void* d_ws, size_t ws_size,
                              hipStream_t stream) {
    const float* r   = (const float*)d_in[0];
    const float* xre = (const float*)d_in[1];
    const float* xim = (const float*)d_in[2];
    const float* Qre = (const float*)d_in[3];
    const float* Qim = (const float*)d_in[4];
    float* out = (float*)d_out;

    const int q_floats = out_size - XT_FLOATS;
    const int qmode  = (q_floats >= 525312) ? 2 : 1;
    const int xt_off = (qmode == 2) ? 525312 : 262656;
    const int nq4 = xt_off / 4;
    const int qb4 = xt_off / (4 * 8);
    const int nt4 = nq4 + XT_FLOATS / 4;

    iss_main <<<NBF, 256, 0, stream>>>(r, xre, xim, Qre, Qim, out, qmode, xt_off);
    iss_scale<<<8,   256, 0, stream>>>();
    iss_norm <<<4096,256, 0, stream>>>(out, nq4, qb4, nt4);
}

// Round 5
// 398.516 us; speedup vs baseline: 1.6713x; 1.6713x over previous
//
#include <hip/hip_runtime.h>
#include <math.h>

#define NBF 4104             // B*F = 8*513
#define XT_FLOATS 16809984   // 8*513*8*512

// Static device scratch; fully overwritten before read each call -> deterministic.
__device__ float d_partials[NBF];
__device__ float d_scales[8];

// NOTE: no min-waves clause. Round 4's (256,4) capped VGPR at 64 -> ~570 MB of
// scratch-spill HBM traffic (FETCH 99.9->739 MB) and +27% time. Phase A needs
// ~96 live VGPRs; let the allocator have them (round 3: 184 VGPR, zero spill).
__global__ __launch_bounds__(256) void iss_main(
    const float* __restrict__ g_r,
    const float* __restrict__ g_xre,
    const float* __restrict__ g_xim,
    const float* __restrict__ g_Qre,
    const float* __restrict__ g_Qim,
    float* __restrict__ g_out,
    const int qmode,        // 2 = interleaved re,im pairs; 1 = real part only
    const int xt_off)       // float offset where the xt region begins
{
    __shared__ float  s_xr[8][512];
    __shared__ float  s_xi[8][512];
    __shared__ float2 s_V [8][8][9];   // padded row stride
    __shared__ float2 s_Q [8][8];
    __shared__ float  s_part[4];

    const int tid = threadIdx.x;
    const int bf  = blockIdx.x;
    const size_t base = (size_t)bf * 4096;

    // ---- stage x_re, x_im into LDS (float4, coalesced); Q into s_Q ----
    {
        const float4* xr4 = (const float4*)(g_xre + base);
        const float4* xi4 = (const float4*)(g_xim + base);
        float4* sxr = (float4*)&s_xr[0][0];
        float4* sxi = (float4*)&s_xi[0][0];
        #pragma unroll
        for (int i = 0; i < 4; ++i) {
            const int idx = tid + (i << 8);
            sxr[idx] = xr4[idx];
            sxi[idx] = xi4[idx];
        }
        if (tid < 64)
            s_Q[tid>>3][tid&7] = make_float2(g_Qre[(size_t)bf*64 + tid],
                                             g_Qim[(size_t)bf*64 + tid]);
    }
    __syncthreads();

    // ---- phase A: V[k][m][n] = (1/T) sum_t max(r,1e-3) x_m conj(x_n) ----
    const int k  = tid >> 5;      // 8 k's, 32 threads each
    const int tc = tid & 31;
    // prefetch r straight from global (single-use; no LDS staging)
    float rbuf[16];
    {
        const float* rrow = g_r + base + (k << 9) + tc;
        #pragma unroll
        for (int it = 0; it < 16; ++it) rbuf[it] = rrow[it << 5];
    }

    float accd[8] = {0,0,0,0,0,0,0,0};
    float accr[28], acci[28];
    #pragma unroll
    for (int p = 0; p < 28; ++p) { accr[p] = 0.f; acci[p] = 0.f; }

    #pragma unroll
    for (int it = 0; it < 16; ++it) {
        const int t = tc + (it << 5);
        const float rw = fmaxf(rbuf[it], 1e-3f);
        float xr[8], xi[8];
        #pragma unroll
        for (int m = 0; m < 8; ++m) { xr[m] = s_xr[m][t]; xi[m] = s_xi[m][t]; }
        int p = 0;
        #pragma unroll
        for (int m = 0; m < 8; ++m) {
            const float yr = rw * xr[m], yi = rw * xi[m];
            accd[m] += yr*xr[m] + yi*xi[m];
            #pragma unroll
            for (int n = m+1; n < 8; ++n, ++p) {
                accr[p] += yr*xr[n] + yi*xi[n];
                acci[p] += yi*xr[n] - yr*xi[n];
            }
        }
    }

    // butterfly reduce across the 32 threads sharing k (offsets<=16 stay in half-wave)
    #pragma unroll
    for (int m = 0; m < 8; ++m) {
        #pragma unroll
        for (int off = 16; off >= 1; off >>= 1) accd[m] += __shfl_xor(accd[m], off, 64);
    }
    #pragma unroll
    for (int p = 0; p < 28; ++p) {
        #pragma unroll
        for (int off = 16; off >= 1; off >>= 1) accr[p] += __shfl_xor(accr[p], off, 64);
        #pragma unroll
        for (int off = 16; off >= 1; off >>= 1) acci[p] += __shfl_xor(acci[p], off, 64);
    }

    if (tc == 0) {
        const float invT = 1.0f / 512.0f;
        float d[8]; float tr = 0.f;
        #pragma unroll
        for (int m = 0; m < 8; ++m) { d[m] = accd[m]*invT; tr += d[m]; }
        const float e = fmaxf(tr, 1.0f) * 1e-6f;
        #pragma unroll
        for (int m = 0; m < 8; ++m) s_V[k][m][m] = make_float2(d[m] + e, 0.f);
        int p = 0;
        #pragma unroll
        for (int m = 0; m < 8; ++m) {
            #pragma unroll
            for (int n = m+1; n < 8; ++n, ++p) {
                const float vr = accr[p]*invT, vi = acci[p]*invT;
                s_V[k][m][n] = make_float2(vr,  vi);
                s_V[k][n][m] = make_float2(vr, -vi);
            }
        }
    }
    __syncthreads();

    // ---- phase B: wave-synchronous, zero barriers, all waves redundant ----
    // lane (kp,mm) owns Q[kp][mm]; V row kept in registers; row-kk of Q via shuffles.
    {
        const int lane = tid & 63;
        const int kp = lane >> 3, mm = lane & 7;
        float vRr[8], vRi[8];
        #pragma unroll
        for (int n = 0; n < 8; ++n) {
            const float2 V = s_V[kp][mm][n];
            vRr[n] = V.x; vRi[n] = V.y;
        }
        const float2 Q0 = s_Q[kp][mm];
        float qre = Q0.x, qim = Q0.y;

        #pragma unroll
        for (int step = 0; step < 16; ++step) {
            const int kk = step & 7;
            // snapshot row kk of Q (pre-update values)
            float qnr[8], qni[8];
            #pragma unroll
            for (int n = 0; n < 8; ++n) {
                qnr[n] = __shfl(qre, (kk<<3)+n, 64);
                qni[n] = __shfl(qim, (kk<<3)+n, 64);
            }
            const float qmr = __shfl(qre, (kk<<3)+mm, 64);  // q_old[own m]
            const float qmi = __shfl(qim, (kk<<3)+mm, 64);

            // Vq = V_row . conj(q)
            float vqr = 0.f, vqi = 0.f;
            #pragma unroll
            for (int n = 0; n < 8; ++n) {
                vqr += vRr[n]*qnr[n] + vRi[n]*qni[n];
                vqi += vRi[n]*qnr[n] - vRr[n]*qni[n];
            }
            // p_m = Re(q_m * Vq_m);  t = Q_own * Vq_own (no conj)
            float p   = qmr*vqr - qmi*vqi;
            float tre = qre*vqr - qim*vqi;
            float tim = qre*vqi + qim*vqr;
            // reduce over m within each 8-lane group (lane bits 0..2)
            #pragma unroll
            for (int off = 1; off < 8; off <<= 1) {
                p   += __shfl_xor(p,   off, 64);
                tre += __shfl_xor(tre, off, 64);
                tim += __shfl_xor(tim, off, 64);
            }
            const float qvq = fmaxf(p, 1e-6f);
            float vr_, vi_;
            if (kp == kk) { vr_ = 1.0f - rsqrtf(qvq); vi_ = 0.f; }
            else { const float inv = 1.0f / qvq; vr_ = tre*inv; vi_ = tim*inv; }
            // Q_own -= v * q_old[m]
            qre -= vr_*qmr - vi_*qmi;
            qim -= vr_*qmi + vi_*qmr;
        }

        if (tid < 64) {
            s_Q[kp][mm] = make_float2(qre, qim);
            if (qmode == 2) {
                g_out[(size_t)bf*128 + tid*2]     = qre;
                g_out[(size_t)bf*128 + tid*2 + 1] = qim;
            } else {
                g_out[(size_t)bf*64 + tid] = qre;
            }
        }
    }
    __syncthreads();

    // ---- phase C: xt = |Q x|^2 (unnormalized), float4 I/O, block partial sum ----
    float lsum = 0.f;
    float* out_xt = g_out + xt_off;
    #pragma unroll
    for (int j = 0; j < 4; ++j) {
        const int idx4 = tid + (j << 8);       // 1024 float4 slots
        const int m  = idx4 >> 7;
        const int t0 = (idx4 & 127) << 2;      // 4 consecutive t
        float qxr[4] = {0,0,0,0}, qxi[4] = {0,0,0,0};
        #pragma unroll
        for (int n = 0; n < 8; ++n) {
            const float2 Qv = s_Q[m][n];
            const float4 xr = *(const float4*)&s_xr[n][t0];
            const float4 xi = *(const float4*)&s_xi[n][t0];
            qxr[0] += Qv.x*xr.x - Qv.y*xi.x;  qxi[0] += Qv.x*xi.x + Qv.y*xr.x;
            qxr[1] += Qv.x*xr.y - Qv.y*xi.y;  qxi[1] += Qv.x*xi.y + Qv.y*xr.y;
            qxr[2] += Qv.x*xr.z - Qv.y*xi.z;  qxi[2] += Qv.x*xi.z + Qv.y*xr.z;
            qxr[3] += Qv.x*xr.w - Qv.y*xi.w;  qxi[3] += Qv.x*xi.w + Qv.y*xr.w;
        }
        float4 pw;
        pw.x = qxr[0]*qxr[0] + qxi[0]*qxi[0];
        pw.y = qxr[1]*qxr[1] + qxi[1]*qxi[1];
        pw.z = qxr[2]*qxr[2] + qxi[2]*qxi[2];
        pw.w = qxr[3]*qxr[3] + qxi[3]*qxi[3];
        *(float4*)&out_xt[base + ((size_t)idx4 << 2)] = pw;
        lsum += pw.x + pw.y + pw.z + pw.w;
    }
    #pragma unroll
    for (int off = 32; off >= 1; off >>= 1) lsum += __shfl_xor(lsum, off, 64);
    if ((tid & 63) == 0) s_part[tid >> 6] = lsum;
    __syncthreads();
    if (tid == 0) d_partials[bf] = s_part[0] + s_part[1] + s_part[2] + s_part[3];
}

__global__ __launch_bounds__(256) void iss_scale()
{
    const int b = blockIdx.x, tid = threadIdx.x;
    __shared__ float sp[4];
    float s = 0.f;
    for (int i = tid; i < 513; i += 256) s += d_partials[b*513 + i];
    #pragma unroll
    for (int off = 32; off >= 1; off >>= 1) s += __shfl_xor(s, off, 64);
    if ((tid & 63) == 0) sp[tid >> 6] = s;
    __syncthreads();
    if (tid == 0) d_scales[b] = (sp[0]+sp[1]+sp[2]+sp[3]) / (513.0f * 8.0f * 512.0f);
}

__global__ __launch_bounds__(256) void iss_norm(
    float* __restrict__ g_out,
    const int nq4,     // Q region in float4s  (= xt_off/4)
    const int qb4,     // float4s per batch in Q region
    const int nt4)     // total float4s (= out_size/4)
{
    float4* o4 = (float4*)g_out;
    for (int i = blockIdx.x*256 + threadIdx.x; i < nt4; i += gridDim.x*256) {
        float s;
        if (i < nq4) {
            const int b = i / qb4;
            s = rsqrtf(fmaxf(d_scales[b], 1e-6f));
        } else {
            const int j = i - nq4;
            const int b = j / 525312;          // xt float4s per batch
            s = 1.0f / d_scales[b];
        }
        float4 v = o4[i];
        v.x *= s; v.y *= s; v.z *= s; v.w *= s;
        o4[i] = v;
    }
}

extern "C" void kernel_launch(void* const* d_in, const int* in_sizes, int n_in,
                              void* d_out, int out_size, void* d_ws, size_t ws_size,
                              hipStream_t stream) {
    const float* r   = (const float*)d_in[0];
    const float* xre = (const float*)d_in[1];
    const float* xim = (const float*)d_in[2];
    const float* Qre = (const float*)d_in[3];
    const float* Qim = (const float*)d_in[4];
    float* out = (float*)d_out;

    const int q_floats = out_size - XT_FLOATS;
    const int qmode  = (q_floats >= 525312) ? 2 : 1;
    const int xt_off = (qmode == 2) ? 525312 : 262656;
    const int nq4 = xt_off / 4;
    const int qb4 = xt_off / (4 * 8);
    const int nt4 = nq4 + XT_FLOATS / 4;

    iss_main <<<NBF, 256, 0, stream>>>(r, xre, xim, Qre, Qim, out, qmode, xt_off);
    iss_scale<<<8,   256, 0, stream>>>();
    iss_norm <<<4096,256, 0, stream>>>(out, nq4, qb4, nt4);
}